// Round 14
// baseline (121.495 us; speedup 1.0000x reference)
//
#include <hip/hip_runtime.h>

typedef __attribute__((ext_vector_type(8))) short short8;
typedef __attribute__((ext_vector_type(4))) short shortx4;
typedef __attribute__((ext_vector_type(4))) float floatx4;
typedef __attribute__((ext_vector_type(4))) _Float16 half4;
typedef __attribute__((ext_vector_type(2))) _Float16 half2v;

__device__ __forceinline__ short bf16_short(float f) {
    unsigned u = __builtin_bit_cast(unsigned, f);
    u = (u + 0x7fff + ((u >> 16) & 1)) >> 16;   // RNE, finite values only
    return (short)u;
}

__device__ __forceinline__ float fast_exp2(float x) {
#if __has_builtin(__builtin_amdgcn_exp2f)
    return __builtin_amdgcn_exp2f(x);
#else
    return __expf(x * 0.6931471805599453f);
#endif
}

__device__ __forceinline__ half4 pk4(float p0, float p1, float p2, float p3) {
#if __has_builtin(__builtin_amdgcn_cvt_pkrtz)
    half2v lo = __builtin_bit_cast(half2v, __builtin_amdgcn_cvt_pkrtz(p0, p1));
    half2v hi = __builtin_bit_cast(half2v, __builtin_amdgcn_cvt_pkrtz(p2, p3));
    half4 o; o[0] = lo[0]; o[1] = lo[1]; o[2] = hi[0]; o[3] = hi[1];
    return o;
#else
    half4 o; o[0] = (_Float16)p0; o[1] = (_Float16)p1;
    o[2] = (_Float16)p2; o[3] = (_Float16)p3;
    return o;
#endif
}

// ---------------------------------------------------------------------------
// Kernel 1: one-time data prep.
// Blocks [0,2368): weights fp32 -> bf16 MFMA A-layout.
//   Wt:  [tap(9)][cog(4)][chunk(16)][co(128)][j(8)]  (ci = chunk*8+j)
//   Wot: [chunk(16)][co(128)][j(8)]
// Blocks [2368,2944): X fp32 -> bf16 fragment layout
//   Xt:  [b(4)][chunk(16)][row(48)][col(48)][j(8)]   (ci = chunk*8+j)
// ---------------------------------------------------------------------------
__global__ __launch_bounds__(256) void transform_w(
    const float* __restrict__ wi, const float* __restrict__ wq,
    const float* __restrict__ wo, const float* __restrict__ x,
    short* __restrict__ Wt, short* __restrict__ Wot, short* __restrict__ Xt)
{
    if (blockIdx.x < 2368) {
        int idx = blockIdx.x * 256 + threadIdx.x;
        if (idx < 589824) {
            int j  = idx & 7;
            int t1 = idx >> 3;
            int co = t1 & 127;
            int t2 = t1 >> 7;
            int chunk = t2 & 15;
            int t3 = t2 >> 4;
            int cog = t3 & 3;
            int tap = t3 >> 2;
            int ci = chunk * 8 + j;
            float v;
            if (cog == 0) v = wi[(co * 128 + ci) * 9 + tap];
            else          v = wq[((((cog - 1) * 128) + co) * 128 + ci) * 9 + tap];
            Wt[idx] = bf16_short(v);
        } else {
            int i2 = idx - 589824;
            int j  = i2 & 7;
            int co = (i2 >> 3) & 127;
            int chunk = i2 >> 10;
            int ci = chunk * 8 + j;
            Wot[i2] = bf16_short(wo[co * 128 + ci]);
        }
    } else {
        // X transpose+convert: xid over [b][chunk][row][col]
        int xid = (blockIdx.x - 2368) * 256 + threadIdx.x;   // 0..147455
        int col   = xid % 48;
        int row   = (xid / 48) % 48;
        int chunk = (xid / 2304) % 16;
        int b     = xid / 36864;
        const float* xs = x + ((b * 128 + chunk * 8) * 48 + row) * 48 + col;
        short8 o;
        #pragma unroll
        for (int j = 0; j < 8; ++j) o[j] = bf16_short(xs[j * 2304]);
        *(short8*)&Xt[(size_t)xid * 8] = o;
    }
}

// ---------------------------------------------------------------------------
// Kernel 2: fused circular 3x3 convs (init 128ch + qkv 384ch), implicit GEMM.
// R14 change: cog==3 writes vA in tile-blocked PV A-fragment layout
//   vA[bh][s(144)][d(16)][m(16)]  (s = n/16, m = n%16 = l16, d = quad*4+r)
// so attention's V loads become contiguous half4 (8 cache lines/load, was 64).
// ---------------------------------------------------------------------------
__global__ __launch_bounds__(256) void conv_main(
    const short* __restrict__ Xt, const short* __restrict__ Wt,
    float* __restrict__ dout, _Float16* __restrict__ qT,
    _Float16* __restrict__ kT, _Float16* __restrict__ vA)
{
    const int y   = blockIdx.x;   // 0..47
    const int cog = blockIdx.y;   // 0..3
    const int b   = blockIdx.z;   // 0..3

    __shared__ short Xs[16 * 3 * 48 * 8];   // [(chunk*3+row)*48+col]*8+j

    const int t = threadIdx.x;
    const int wave = t >> 6, lane = t & 63, quad = lane >> 4, l16 = lane & 15;

    const short* wA = Wt + (size_t)cog * 16384 + (wave * 32 + l16) * 8;

    short8 A[2][8];   // [buf][kk*2+half], double-buffered across taps
    #pragma unroll
    for (int kk = 0; kk < 4; ++kk) {
        int chA = kk * 4 + quad;
        A[0][kk * 2 + 0] = *(const short8*)(wA + chA * 1024);
        A[0][kk * 2 + 1] = *(const short8*)(wA + chA * 1024 + 128);
    }

    // Stage X rows y-1,y,y+1 (wrapped): pure b128 copies from Xt
    {
        const short* xtb = Xt + (size_t)b * 16 * 48 * 48 * 8;
        #pragma unroll
        for (int it = 0; it < 9; ++it) {
            int w     = it * 256 + t;        // 0..2303
            int col   = w % 48;
            int row3  = (w / 48) % 3;
            int chunk = w / 144;
            int rowg  = y + row3 - 1;
            rowg = (rowg < 0) ? rowg + 48 : (rowg >= 48 ? rowg - 48 : rowg);
            short8 v = *(const short8*)&xtb[((chunk * 48 + rowg) * 48 + col) * 8];
            *(short8*)&Xs[((chunk * 3 + row3) * 48 + col) * 8] = v;
        }
    }

    floatx4 acc[2][3];
    #pragma unroll
    for (int i = 0; i < 2; ++i)
        #pragma unroll
        for (int jn = 0; jn < 3; ++jn) acc[i][jn] = (floatx4){0.f, 0.f, 0.f, 0.f};

    __syncthreads();   // the only barrier: Xs ready

    #pragma unroll
    for (int tap = 0; tap < 9; ++tap) {
        const int cur = tap & 1;
        if (tap < 8) {
            const short* wn = wA + (tap + 1) * 65536;
            #pragma unroll
            for (int kk = 0; kk < 4; ++kk) {
                int chA = kk * 4 + quad;
                A[cur ^ 1][kk * 2 + 0] = *(const short8*)(wn + chA * 1024);
                A[cur ^ 1][kk * 2 + 1] = *(const short8*)(wn + chA * 1024 + 128);
            }
        }

        const int dy = tap / 3, dx = tap % 3;
        int colw[3];
        #pragma unroll
        for (int nt = 0; nt < 3; ++nt) {
            int c = nt * 16 + l16 + dx - 1;
            c = (c < 0) ? c + 48 : (c >= 48 ? c - 48 : c);
            colw[nt] = c;
        }

        #pragma unroll
        for (int kk = 0; kk < 4; ++kk) {
            int chA = kk * 4 + quad;
            short8 a0 = A[cur][kk * 2 + 0];
            short8 a1 = A[cur][kk * 2 + 1];
            #pragma unroll
            for (int nt = 0; nt < 3; ++nt) {
                short8 bf = *(const short8*)&Xs[((chA * 3 + dy) * 48 + colw[nt]) * 8];
                acc[0][nt] = __builtin_amdgcn_mfma_f32_16x16x32_bf16(a0, bf, acc[0][nt], 0, 0, 0);
                acc[1][nt] = __builtin_amdgcn_mfma_f32_16x16x32_bf16(a1, bf, acc[1][nt], 0, 0, 0);
            }
        }
    }

    // Epilogue: C/D layout col=l16 (spatial), row=quad*4+r (co)
    if (cog == 0) {
        #pragma unroll
        for (int mt = 0; mt < 2; ++mt)
            #pragma unroll
            for (int nt = 0; nt < 3; ++nt)
                #pragma unroll
                for (int r = 0; r < 4; ++r) {
                    int n    = y * 48 + nt * 16 + l16;
                    int co_l = wave * 32 + mt * 16 + quad * 4 + r;
                    dout[(b * 256 + co_l) * 2304 + n] = acc[mt][nt][r];
                }
    } else if (cog == 3) {
        // vA[bh][s][d][m]: s = y*3+nt, d = quad*4+r, m = l16, h = wave*2+mt
        #pragma unroll
        for (int mt = 0; mt < 2; ++mt) {
            int hh = wave * 2 + mt;
            #pragma unroll
            for (int nt = 0; nt < 3; ++nt) {
                int s = y * 3 + nt;
                _Float16* dst = vA + (((size_t)(b * 8 + hh) * 144 + s) * 16) * 16 + l16;
                #pragma unroll
                for (int r = 0; r < 4; ++r)
                    dst[(quad * 4 + r) * 16] = (_Float16)acc[mt][nt][r];
            }
        }
    } else {
        _Float16* dst = (cog == 1) ? qT : kT;
        const float scale = (cog == 1) ? 0.360673762f : 1.0f;   // 0.25*log2(e) for q
        #pragma unroll
        for (int mt = 0; mt < 2; ++mt) {
            int hh = wave * 2 + mt;           // head index (co_l>>4)
            #pragma unroll
            for (int nt = 0; nt < 3; ++nt) {
                int n = y * 48 + nt * 16 + l16;
                half4 o;
                #pragma unroll
                for (int r = 0; r < 4; ++r) o[r] = (_Float16)(acc[mt][nt][r] * scale);
                *(half4*)&dst[((b * 8 + hh) * 2304 + n) * 16 + quad * 4] = o;
            }
        }
    }
}

// ---------------------------------------------------------------------------
// Kernel 3: flash attention, register-only P, 4x Q-reuse, dual A/B streams.
// R14: V loads from tile-blocked vA[bh][s][d][m] -> contiguous half4/lane
// (8 cache lines per load instruction, was 64 with the [c][n] gather).
// attnbuf (bf16) layout (b, h, n, d) flat == raw reshape to (b,128,2304).
// ---------------------------------------------------------------------------
__global__ __launch_bounds__(256) void attn_kernel(
    const _Float16* __restrict__ qT, const _Float16* __restrict__ kT,
    const _Float16* __restrict__ vA, short* __restrict__ attnbuf)
{
    const int bh = blockIdx.y;
    const int n0 = blockIdx.x * 64;

    __shared__ float Red[4][4][64][5];   // [wave][frag][lane][accO x4, lsum]

    const int t = threadIdx.x;
    const int wave = t >> 6, lane = t & 63, quad = lane >> 4, l16 = lane & 15;

    const _Float16* qTb = qT + (size_t)bh * 2304 * 16;
    const _Float16* kTb = kT + (size_t)bh * 2304 * 16;
    const _Float16* vAb = vA + (size_t)bh * 144 * 256;

    half4 qf[4];
    #pragma unroll
    for (int f = 0; f < 4; ++f)
        qf[f] = *(const half4*)(qTb + (n0 + f * 16 + l16) * 16 + quad * 4);

    floatx4 accA[4], accB[4];
    float lsum[4];
    #pragma unroll
    for (int f = 0; f < 4; ++f) {
        accA[f] = (floatx4){0.f,0.f,0.f,0.f};
        accB[f] = (floatx4){0.f,0.f,0.f,0.f};
        lsum[f] = 0.f;
    }

    const int mbase = wave * 576;        // m-rows; subtile base sig0 = wave*36
    const int sig0  = wave * 36;
    const int vofs  = l16 * 16 + quad * 4;   // within-subtile V offset

    half4 kfA = *(const half4*)(kTb + (mbase + l16) * 16 + quad * 4);
    half4 vfA = *(const half4*)(vAb + sig0 * 256 + vofs);
    half4 kfB = *(const half4*)(kTb + (mbase + 16 + l16) * 16 + quad * 4);
    half4 vfB = *(const half4*)(vAb + (sig0 + 1) * 256 + vofs);

    #pragma unroll 2
    for (int s = 0; s < 18; ++s) {
        half4 kA = kfA, vAc = vfA, kB = kfB, vBc = vfB;
        if (s < 17) {
            int m1 = mbase + (s + 1) * 32;
            int sg = sig0 + (s + 1) * 2;
            kfA = *(const half4*)(kTb + (m1 + l16) * 16 + quad * 4);
            vfA = *(const half4*)(vAb + sg * 256 + vofs);
            kfB = *(const half4*)(kTb + (m1 + 16 + l16) * 16 + quad * 4);
            vfB = *(const half4*)(vAb + (sg + 1) * 256 + vofs);
        }
        floatx4 z = {0.f,0.f,0.f,0.f};
        floatx4 stA[4], stB[4];
        #pragma unroll
        for (int f = 0; f < 4; ++f)
            stA[f] = __builtin_amdgcn_mfma_f32_16x16x16f16(kA, qf[f], z, 0, 0, 0);
        #pragma unroll
        for (int f = 0; f < 4; ++f)
            stB[f] = __builtin_amdgcn_mfma_f32_16x16x16f16(kB, qf[f], z, 0, 0, 0);

        #pragma unroll
        for (int f = 0; f < 4; ++f) {
            float a0 = fast_exp2(stA[f][0]);
            float a1 = fast_exp2(stA[f][1]);
            float a2 = fast_exp2(stA[f][2]);
            float a3 = fast_exp2(stA[f][3]);
            lsum[f] += (a0 + a1) + (a2 + a3);
            accA[f] = __builtin_amdgcn_mfma_f32_16x16x16f16(vAc, pk4(a0,a1,a2,a3), accA[f], 0, 0, 0);
        }
        #pragma unroll
        for (int f = 0; f < 4; ++f) {
            float b0 = fast_exp2(stB[f][0]);
            float b1 = fast_exp2(stB[f][1]);
            float b2 = fast_exp2(stB[f][2]);
            float b3 = fast_exp2(stB[f][3]);
            lsum[f] += (b0 + b1) + (b2 + b3);
            accB[f] = __builtin_amdgcn_mfma_f32_16x16x16f16(vBc, pk4(b0,b1,b2,b3), accB[f], 0, 0, 0);
        }
    }

    #pragma unroll
    for (int f = 0; f < 4; ++f) {
        lsum[f] += __shfl_xor(lsum[f], 16, 64);
        lsum[f] += __shfl_xor(lsum[f], 32, 64);
    }

    #pragma unroll
    for (int f = 0; f < 4; ++f) {
        #pragma unroll
        for (int r = 0; r < 4; ++r) Red[wave][f][lane][r] = accA[f][r] + accB[f][r];
        Red[wave][f][lane][4] = lsum[f];
    }
    __syncthreads();

    {
        const int f = wave;
        float tot[4] = {0.f, 0.f, 0.f, 0.f};
        float ls = 0.f;
        #pragma unroll
        for (int w = 0; w < 4; ++w) {
            #pragma unroll
            for (int r = 0; r < 4; ++r) tot[r] += Red[w][f][lane][r];
            ls += Red[w][f][lane][4];
        }
        float rinv = 1.0f / ls;
        shortx4 o;
        #pragma unroll
        for (int r = 0; r < 4; ++r) o[r] = bf16_short(tot[r] * rinv);
        int n = n0 + f * 16 + l16;
        *(shortx4*)&attnbuf[((size_t)bh * 2304 + n) * 16 + quad * 4] = o;
    }
}

// ---------------------------------------------------------------------------
// Kernel 4: 1x1 conv on raw-reshaped attention buffer. M=128, N=32, K=128.
// (unchanged from R11)
// ---------------------------------------------------------------------------
__global__ __launch_bounds__(256) void conv1x1(
    const short* __restrict__ attnbuf, const short* __restrict__ Wot,
    float* __restrict__ dout)
{
    const int b    = blockIdx.y;
    const int col0 = blockIdx.x * 32;
    constexpr int RSA = 136;              // row stride (shorts), 16B-aligned

    __shared__ short Wo[16 * 128 * 8];
    __shared__ short As[32 * RSA];        // [col][ci]

    const int t = threadIdx.x;
    {   // Wo: contiguous copy
        short8* dst = (short8*)Wo;
        const short8* src = (const short8*)Wot;
        #pragma unroll
        for (int it = 0; it < 8; ++it) dst[it * 256 + t] = src[it * 256 + t];
    }
    {   // As: transpose 128ci x 32col -> [col][ci]
        const short* ab = attnbuf + b * 128 * 2304;
        #pragma unroll
        for (int it = 0; it < 8; ++it) {
            int e = it * 256 + t;
            int ci = e >> 4, cp = e & 15;
            unsigned v = *(const unsigned*)(ab + ci * 2304 + col0 + cp * 2);
            As[(cp * 2) * RSA + ci]     = (short)(v & 0xffff);
            As[(cp * 2 + 1) * RSA + ci] = (short)(v >> 16);
        }
    }
    __syncthreads();

    const int wave = t >> 6, lane = t & 63, quad = lane >> 4, l16 = lane & 15;
    floatx4 acc[2][2];
    #pragma unroll
    for (int i = 0; i < 2; ++i)
        #pragma unroll
        for (int j = 0; j < 2; ++j) acc[i][j] = (floatx4){0.f, 0.f, 0.f, 0.f};

    #pragma unroll
    for (int kk = 0; kk < 4; ++kk) {
        int chA = kk * 4 + quad;
        short8 a0 = *(const short8*)&Wo[(chA * 128 + wave * 32 + l16) * 8];
        short8 a1 = *(const short8*)&Wo[(chA * 128 + wave * 32 + 16 + l16) * 8];
        #pragma unroll
        for (int nt = 0; nt < 2; ++nt) {
            short8 bf = *(const short8*)&As[(nt * 16 + l16) * RSA + kk * 32 + quad * 8];
            acc[0][nt] = __builtin_amdgcn_mfma_f32_16x16x32_bf16(a0, bf, acc[0][nt], 0, 0, 0);
            acc[1][nt] = __builtin_amdgcn_mfma_f32_16x16x32_bf16(a1, bf, acc[1][nt], 0, 0, 0);
        }
    }

    #pragma unroll
    for (int mt = 0; mt < 2; ++mt)
        #pragma unroll
        for (int nt = 0; nt < 2; ++nt)
            #pragma unroll
            for (int r = 0; r < 4; ++r) {
                int co  = wave * 32 + mt * 16 + quad * 4 + r;
                int col = col0 + nt * 16 + l16;
                dout[(b * 256 + 128 + co) * 2304 + col] = acc[mt][nt][r];  // fp32 out
            }
}

// ---------------------------------------------------------------------------
extern "C" void kernel_launch(void* const* d_in, const int* in_sizes, int n_in,
                              void* d_out, int out_size, void* d_ws, size_t ws_size,
                              hipStream_t stream)
{
    const float* x  = (const float*)d_in[0];
    const float* wi = (const float*)d_in[1];
    const float* wq = (const float*)d_in[2];
    const float* wo = (const float*)d_in[3];
    float* dout = (float*)d_out;

    char* ws = (char*)d_ws;
    _Float16* qT   = (_Float16*)(ws);                   // 2,359,296 B
    _Float16* kT   = (_Float16*)(ws + 2359296);         // 2,359,296 B
    _Float16* vA   = (_Float16*)(ws + 4718592);         // 2,359,296 B (tile-blocked)
    short* attnbuf = (short*)(ws + 7077888);            // 2,359,296 B (bf16)
    short* Wt      = (short*)(ws + 9437184);            // 1,179,648 B
    short* Wot     = (short*)(ws + 10616832);           // 32,768 B
    short* Xt      = (short*)(ws + 10649600);           // 2,359,296 B

    transform_w<<<2944, 256, 0, stream>>>(wi, wq, wo, x, Wt, Wot, Xt);
    conv_main<<<dim3(48, 4, 4), 256, 0, stream>>>(Xt, Wt, dout, qT, kT, vA);
    attn_kernel<<<dim3(36, 32), 256, 0, stream>>>(qT, kT, vA, attnbuf);
    conv1x1<<<dim3(72, 4), 256, 0, stream>>>(attnbuf, Wot, dout);
}

// Round 15
// 117.608 us; speedup vs baseline: 1.0331x; 1.0331x over previous
//
#include <hip/hip_runtime.h>

typedef __attribute__((ext_vector_type(8))) short short8;
typedef __attribute__((ext_vector_type(4))) short shortx4;
typedef __attribute__((ext_vector_type(4))) float floatx4;
typedef __attribute__((ext_vector_type(4))) _Float16 half4;
typedef __attribute__((ext_vector_type(2))) _Float16 half2v;

__device__ __forceinline__ short bf16_short(float f) {
    unsigned u = __builtin_bit_cast(unsigned, f);
    u = (u + 0x7fff + ((u >> 16) & 1)) >> 16;   // RNE, finite values only
    return (short)u;
}

__device__ __forceinline__ float fast_exp2(float x) {
#if __has_builtin(__builtin_amdgcn_exp2f)
    return __builtin_amdgcn_exp2f(x);
#else
    return __expf(x * 0.6931471805599453f);
#endif
}

__device__ __forceinline__ half4 pk4(float p0, float p1, float p2, float p3) {
#if __has_builtin(__builtin_amdgcn_cvt_pkrtz)
    half2v lo = __builtin_bit_cast(half2v, __builtin_amdgcn_cvt_pkrtz(p0, p1));
    half2v hi = __builtin_bit_cast(half2v, __builtin_amdgcn_cvt_pkrtz(p2, p3));
    half4 o; o[0] = lo[0]; o[1] = lo[1]; o[2] = hi[0]; o[3] = hi[1];
    return o;
#else
    half4 o; o[0] = (_Float16)p0; o[1] = (_Float16)p1;
    o[2] = (_Float16)p2; o[3] = (_Float16)p3;
    return o;
#endif
}

// ---------------------------------------------------------------------------
// Kernel 1: one-time data prep.
// Blocks [0,2368): weights fp32 -> bf16 MFMA A-layout.
//   Wt:  [tap(9)][cog(4)][chunk(16)][co(128)][j(8)]  (ci = chunk*8+j)
//   Wot: [chunk(16)][co(128)][j(8)]
// Blocks [2368,2944): X fp32 -> bf16 fragment layout
//   Xt:  [b(4)][chunk(16)][row(48)][col(48)][j(8)]   (ci = chunk*8+j)
// ---------------------------------------------------------------------------
__global__ __launch_bounds__(256) void transform_w(
    const float* __restrict__ wi, const float* __restrict__ wq,
    const float* __restrict__ wo, const float* __restrict__ x,
    short* __restrict__ Wt, short* __restrict__ Wot, short* __restrict__ Xt)
{
    if (blockIdx.x < 2368) {
        int idx = blockIdx.x * 256 + threadIdx.x;
        if (idx < 589824) {
            int j  = idx & 7;
            int t1 = idx >> 3;
            int co = t1 & 127;
            int t2 = t1 >> 7;
            int chunk = t2 & 15;
            int t3 = t2 >> 4;
            int cog = t3 & 3;
            int tap = t3 >> 2;
            int ci = chunk * 8 + j;
            float v;
            if (cog == 0) v = wi[(co * 128 + ci) * 9 + tap];
            else          v = wq[((((cog - 1) * 128) + co) * 128 + ci) * 9 + tap];
            Wt[idx] = bf16_short(v);
        } else {
            int i2 = idx - 589824;
            int j  = i2 & 7;
            int co = (i2 >> 3) & 127;
            int chunk = i2 >> 10;
            int ci = chunk * 8 + j;
            Wot[i2] = bf16_short(wo[co * 128 + ci]);
        }
    } else {
        // X transpose+convert: xid over [b][chunk][row][col]
        int xid = (blockIdx.x - 2368) * 256 + threadIdx.x;   // 0..147455
        int col   = xid % 48;
        int row   = (xid / 48) % 48;
        int chunk = (xid / 2304) % 16;
        int b     = xid / 36864;
        const float* xs = x + ((b * 128 + chunk * 8) * 48 + row) * 48 + col;
        short8 o;
        #pragma unroll
        for (int j = 0; j < 8; ++j) o[j] = bf16_short(xs[j * 2304]);
        *(short8*)&Xt[(size_t)xid * 8] = o;
    }
}

// ---------------------------------------------------------------------------
// Kernel 2: fused circular 3x3 convs, implicit GEMM. R15: K-SPLIT over 8
// waves (512-thread block). Waves 0-3 accumulate chunks 0..7, waves 4-7
// chunks 8..15 (pairwise same co-range) -> 24 waves/CU (was 12) with
// unchanged LDS traffic and unchanged X staging. Partial sums merged via
// the dead Xs LDS region (stride-25 pad), waves 0-3 run the epilogue.
// ---------------------------------------------------------------------------
__global__ __launch_bounds__(512) void conv_main(
    const short* __restrict__ Xt, const short* __restrict__ Wt,
    float* __restrict__ dout, _Float16* __restrict__ qT,
    _Float16* __restrict__ kT, _Float16* __restrict__ vA)
{
    const int y   = blockIdx.x;   // 0..47
    const int cog = blockIdx.y;   // 0..3
    const int b   = blockIdx.z;   // 0..3

    __shared__ short Xs[16 * 3 * 48 * 8];   // 36864 B; reused as float Rs[] later

    const int t = threadIdx.x;
    const int wave = t >> 6, lane = t & 63, quad = lane >> 4, l16 = lane & 15;
    const int wv = wave & 3;        // co-range selector (0..3)
    const int kk0 = (wave >> 2) * 2; // K-half: kk in {kk0, kk0+1}

    const short* wA = Wt + (size_t)cog * 16384 + (wv * 32 + l16) * 8;

    short8 A[2][4];   // [buf][kk*2+half], double-buffered across taps
    #pragma unroll
    for (int kk = 0; kk < 2; ++kk) {
        int chA = (kk0 + kk) * 4 + quad;
        A[0][kk * 2 + 0] = *(const short8*)(wA + chA * 1024);
        A[0][kk * 2 + 1] = *(const short8*)(wA + chA * 1024 + 128);
    }

    // Stage X rows y-1,y,y+1 (wrapped): pure b128 copies from Xt
    {
        const short* xtb = Xt + (size_t)b * 16 * 48 * 48 * 8;
        #pragma unroll
        for (int it = 0; it < 5; ++it) {
            int w = it * 512 + t;            // 0..2303
            if (w < 2304) {
                int col   = w % 48;
                int row3  = (w / 48) % 3;
                int chunk = w / 144;
                int rowg  = y + row3 - 1;
                rowg = (rowg < 0) ? rowg + 48 : (rowg >= 48 ? rowg - 48 : rowg);
                short8 v = *(const short8*)&xtb[((chunk * 48 + rowg) * 48 + col) * 8];
                *(short8*)&Xs[((chunk * 3 + row3) * 48 + col) * 8] = v;
            }
        }
    }

    floatx4 acc[2][3];
    #pragma unroll
    for (int i = 0; i < 2; ++i)
        #pragma unroll
        for (int jn = 0; jn < 3; ++jn) acc[i][jn] = (floatx4){0.f, 0.f, 0.f, 0.f};

    __syncthreads();   // Xs ready

    #pragma unroll
    for (int tap = 0; tap < 9; ++tap) {
        const int cur = tap & 1;
        if (tap < 8) {   // prefetch next tap's A-frags; lands during MFMAs
            const short* wn = wA + (tap + 1) * 65536;
            #pragma unroll
            for (int kk = 0; kk < 2; ++kk) {
                int chA = (kk0 + kk) * 4 + quad;
                A[cur ^ 1][kk * 2 + 0] = *(const short8*)(wn + chA * 1024);
                A[cur ^ 1][kk * 2 + 1] = *(const short8*)(wn + chA * 1024 + 128);
            }
        }

        const int dy = tap / 3, dx = tap % 3;
        int colw[3];
        #pragma unroll
        for (int nt = 0; nt < 3; ++nt) {
            int c = nt * 16 + l16 + dx - 1;
            c = (c < 0) ? c + 48 : (c >= 48 ? c - 48 : c);
            colw[nt] = c;
        }

        #pragma unroll
        for (int kk = 0; kk < 2; ++kk) {
            int chA = (kk0 + kk) * 4 + quad;
            short8 a0 = A[cur][kk * 2 + 0];
            short8 a1 = A[cur][kk * 2 + 1];
            #pragma unroll
            for (int nt = 0; nt < 3; ++nt) {
                short8 bf = *(const short8*)&Xs[((chA * 3 + dy) * 48 + colw[nt]) * 8];
                acc[0][nt] = __builtin_amdgcn_mfma_f32_16x16x32_bf16(a0, bf, acc[0][nt], 0, 0, 0);
                acc[1][nt] = __builtin_amdgcn_mfma_f32_16x16x32_bf16(a1, bf, acc[1][nt], 0, 0, 0);
            }
        }
    }

    // K-split merge: waves 4-7 publish partials through LDS (Xs is dead).
    __syncthreads();   // all waves done reading Xs
    float* Rs = (float*)Xs;   // 4 waves x 64 lanes x stride 25 floats = 25.6 KB
    if (wave >= 4) {
        float* dst = Rs + ((wave - 4) * 64 + lane) * 25;
        #pragma unroll
        for (int mt = 0; mt < 2; ++mt)
            #pragma unroll
            for (int nt = 0; nt < 3; ++nt)
                #pragma unroll
                for (int r = 0; r < 4; ++r) dst[(mt * 3 + nt) * 4 + r] = acc[mt][nt][r];
    }
    __syncthreads();
    if (wave >= 4) return;

    {
        const float* src = Rs + (wave * 64 + lane) * 25;
        #pragma unroll
        for (int mt = 0; mt < 2; ++mt)
            #pragma unroll
            for (int nt = 0; nt < 3; ++nt)
                #pragma unroll
                for (int r = 0; r < 4; ++r) acc[mt][nt][r] += src[(mt * 3 + nt) * 4 + r];
    }

    // Epilogue (waves 0-3): C/D layout col=l16 (spatial), row=quad*4+r (co)
    if (cog == 0) {
        #pragma unroll
        for (int mt = 0; mt < 2; ++mt)
            #pragma unroll
            for (int nt = 0; nt < 3; ++nt)
                #pragma unroll
                for (int r = 0; r < 4; ++r) {
                    int n    = y * 48 + nt * 16 + l16;
                    int co_l = wave * 32 + mt * 16 + quad * 4 + r;
                    dout[(b * 256 + co_l) * 2304 + n] = acc[mt][nt][r];
                }
    } else if (cog == 3) {
        // vA[bh][s][d][m]: s = y*3+nt, d = quad*4+r, m = l16, h = wave*2+mt
        #pragma unroll
        for (int mt = 0; mt < 2; ++mt) {
            int hh = wave * 2 + mt;
            #pragma unroll
            for (int nt = 0; nt < 3; ++nt) {
                int s = y * 3 + nt;
                _Float16* dst = vA + (((size_t)(b * 8 + hh) * 144 + s) * 16) * 16 + l16;
                #pragma unroll
                for (int r = 0; r < 4; ++r)
                    dst[(quad * 4 + r) * 16] = (_Float16)acc[mt][nt][r];
            }
        }
    } else {
        _Float16* dst = (cog == 1) ? qT : kT;
        const float scale = (cog == 1) ? 0.360673762f : 1.0f;   // 0.25*log2(e) for q
        #pragma unroll
        for (int mt = 0; mt < 2; ++mt) {
            int hh = wave * 2 + mt;           // head index (co_l>>4)
            #pragma unroll
            for (int nt = 0; nt < 3; ++nt) {
                int n = y * 48 + nt * 16 + l16;
                half4 o;
                #pragma unroll
                for (int r = 0; r < 4; ++r) o[r] = (_Float16)(acc[mt][nt][r] * scale);
                *(half4*)&dst[((b * 8 + hh) * 2304 + n) * 16 + quad * 4] = o;
            }
        }
    }
}

// ---------------------------------------------------------------------------
// Kernel 3: flash attention, register-only P, 4x Q-reuse, dual A/B streams,
// tile-blocked V. (unchanged from R14)
// ---------------------------------------------------------------------------
__global__ __launch_bounds__(256) void attn_kernel(
    const _Float16* __restrict__ qT, const _Float16* __restrict__ kT,
    const _Float16* __restrict__ vA, short* __restrict__ attnbuf)
{
    const int bh = blockIdx.y;
    const int n0 = blockIdx.x * 64;

    __shared__ float Red[4][4][64][5];   // [wave][frag][lane][accO x4, lsum]

    const int t = threadIdx.x;
    const int wave = t >> 6, lane = t & 63, quad = lane >> 4, l16 = lane & 15;

    const _Float16* qTb = qT + (size_t)bh * 2304 * 16;
    const _Float16* kTb = kT + (size_t)bh * 2304 * 16;
    const _Float16* vAb = vA + (size_t)bh * 144 * 256;

    half4 qf[4];
    #pragma unroll
    for (int f = 0; f < 4; ++f)
        qf[f] = *(const half4*)(qTb + (n0 + f * 16 + l16) * 16 + quad * 4);

    floatx4 accA[4], accB[4];
    float lsum[4];
    #pragma unroll
    for (int f = 0; f < 4; ++f) {
        accA[f] = (floatx4){0.f,0.f,0.f,0.f};
        accB[f] = (floatx4){0.f,0.f,0.f,0.f};
        lsum[f] = 0.f;
    }

    const int mbase = wave * 576;        // m-rows; subtile base sig0 = wave*36
    const int sig0  = wave * 36;
    const int vofs  = l16 * 16 + quad * 4;   // within-subtile V offset

    half4 kfA = *(const half4*)(kTb + (mbase + l16) * 16 + quad * 4);
    half4 vfA = *(const half4*)(vAb + sig0 * 256 + vofs);
    half4 kfB = *(const half4*)(kTb + (mbase + 16 + l16) * 16 + quad * 4);
    half4 vfB = *(const half4*)(vAb + (sig0 + 1) * 256 + vofs);

    #pragma unroll 2
    for (int s = 0; s < 18; ++s) {
        half4 kA = kfA, vAc = vfA, kB = kfB, vBc = vfB;
        if (s < 17) {
            int m1 = mbase + (s + 1) * 32;
            int sg = sig0 + (s + 1) * 2;
            kfA = *(const half4*)(kTb + (m1 + l16) * 16 + quad * 4);
            vfA = *(const half4*)(vAb + sg * 256 + vofs);
            kfB = *(const half4*)(kTb + (m1 + 16 + l16) * 16 + quad * 4);
            vfB = *(const half4*)(vAb + (sg + 1) * 256 + vofs);
        }
        floatx4 z = {0.f,0.f,0.f,0.f};
        floatx4 stA[4], stB[4];
        #pragma unroll
        for (int f = 0; f < 4; ++f)
            stA[f] = __builtin_amdgcn_mfma_f32_16x16x16f16(kA, qf[f], z, 0, 0, 0);
        #pragma unroll
        for (int f = 0; f < 4; ++f)
            stB[f] = __builtin_amdgcn_mfma_f32_16x16x16f16(kB, qf[f], z, 0, 0, 0);

        #pragma unroll
        for (int f = 0; f < 4; ++f) {
            float a0 = fast_exp2(stA[f][0]);
            float a1 = fast_exp2(stA[f][1]);
            float a2 = fast_exp2(stA[f][2]);
            float a3 = fast_exp2(stA[f][3]);
            lsum[f] += (a0 + a1) + (a2 + a3);
            accA[f] = __builtin_amdgcn_mfma_f32_16x16x16f16(vAc, pk4(a0,a1,a2,a3), accA[f], 0, 0, 0);
        }
        #pragma unroll
        for (int f = 0; f < 4; ++f) {
            float b0 = fast_exp2(stB[f][0]);
            float b1 = fast_exp2(stB[f][1]);
            float b2 = fast_exp2(stB[f][2]);
            float b3 = fast_exp2(stB[f][3]);
            lsum[f] += (b0 + b1) + (b2 + b3);
            accB[f] = __builtin_amdgcn_mfma_f32_16x16x16f16(vBc, pk4(b0,b1,b2,b3), accB[f], 0, 0, 0);
        }
    }

    #pragma unroll
    for (int f = 0; f < 4; ++f) {
        lsum[f] += __shfl_xor(lsum[f], 16, 64);
        lsum[f] += __shfl_xor(lsum[f], 32, 64);
    }

    #pragma unroll
    for (int f = 0; f < 4; ++f) {
        #pragma unroll
        for (int r = 0; r < 4; ++r) Red[wave][f][lane][r] = accA[f][r] + accB[f][r];
        Red[wave][f][lane][4] = lsum[f];
    }
    __syncthreads();

    {
        const int f = wave;
        float tot[4] = {0.f, 0.f, 0.f, 0.f};
        float ls = 0.f;
        #pragma unroll
        for (int w = 0; w < 4; ++w) {
            #pragma unroll
            for (int r = 0; r < 4; ++r) tot[r] += Red[w][f][lane][r];
            ls += Red[w][f][lane][4];
        }
        float rinv = 1.0f / ls;
        shortx4 o;
        #pragma unroll
        for (int r = 0; r < 4; ++r) o[r] = bf16_short(tot[r] * rinv);
        int n = n0 + f * 16 + l16;
        *(shortx4*)&attnbuf[((size_t)bh * 2304 + n) * 16 + quad * 4] = o;
    }
}

// ---------------------------------------------------------------------------
// Kernel 4: 1x1 conv on raw-reshaped attention buffer. M=128, N=32, K=128.
// (unchanged from R11)
// ---------------------------------------------------------------------------
__global__ __launch_bounds__(256) void conv1x1(
    const short* __restrict__ attnbuf, const short* __restrict__ Wot,
    float* __restrict__ dout)
{
    const int b    = blockIdx.y;
    const int col0 = blockIdx.x * 32;
    constexpr int RSA = 136;              // row stride (shorts), 16B-aligned

    __shared__ short Wo[16 * 128 * 8];
    __shared__ short As[32 * RSA];        // [col][ci]

    const int t = threadIdx.x;
    {   // Wo: contiguous copy
        short8* dst = (short8*)Wo;
        const short8* src = (const short8*)Wot;
        #pragma unroll
        for (int it = 0; it < 8; ++it) dst[it * 256 + t] = src[it * 256 + t];
    }
    {   // As: transpose 128ci x 32col -> [col][ci]
        const short* ab = attnbuf + b * 128 * 2304;
        #pragma unroll
        for (int it = 0; it < 8; ++it) {
            int e = it * 256 + t;
            int ci = e >> 4, cp = e & 15;
            unsigned v = *(const unsigned*)(ab + ci * 2304 + col0 + cp * 2);
            As[(cp * 2) * RSA + ci]     = (short)(v & 0xffff);
            As[(cp * 2 + 1) * RSA + ci] = (short)(v >> 16);
        }
    }
    __syncthreads();

    const int wave = t >> 6, lane = t & 63, quad = lane >> 4, l16 = lane & 15;
    floatx4 acc[2][2];
    #pragma unroll
    for (int i = 0; i < 2; ++i)
        #pragma unroll
        for (int j = 0; j < 2; ++j) acc[i][j] = (floatx4){0.f, 0.f, 0.f, 0.f};

    #pragma unroll
    for (int kk = 0; kk < 4; ++kk) {
        int chA = kk * 4 + quad;
        short8 a0 = *(const short8*)&Wo[(chA * 128 + wave * 32 + l16) * 8];
        short8 a1 = *(const short8*)&Wo[(chA * 128 + wave * 32 + 16 + l16) * 8];
        #pragma unroll
        for (int nt = 0; nt < 2; ++nt) {
            short8 bf = *(const short8*)&As[(nt * 16 + l16) * RSA + kk * 32 + quad * 8];
            acc[0][nt] = __builtin_amdgcn_mfma_f32_16x16x32_bf16(a0, bf, acc[0][nt], 0, 0, 0);
            acc[1][nt] = __builtin_amdgcn_mfma_f32_16x16x32_bf16(a1, bf, acc[1][nt], 0, 0, 0);
        }
    }

    #pragma unroll
    for (int mt = 0; mt < 2; ++mt)
        #pragma unroll
        for (int nt = 0; nt < 2; ++nt)
            #pragma unroll
            for (int r = 0; r < 4; ++r) {
                int co  = wave * 32 + mt * 16 + quad * 4 + r;
                int col = col0 + nt * 16 + l16;
                dout[(b * 256 + 128 + co) * 2304 + col] = acc[mt][nt][r];  // fp32 out
            }
}

// ---------------------------------------------------------------------------
extern "C" void kernel_launch(void* const* d_in, const int* in_sizes, int n_in,
                              void* d_out, int out_size, void* d_ws, size_t ws_size,
                              hipStream_t stream)
{
    const float* x  = (const float*)d_in[0];
    const float* wi = (const float*)d_in[1];
    const float* wq = (const float*)d_in[2];
    const float* wo = (const float*)d_in[3];
    float* dout = (float*)d_out;

    char* ws = (char*)d_ws;
    _Float16* qT   = (_Float16*)(ws);                   // 2,359,296 B
    _Float16* kT   = (_Float16*)(ws + 2359296);         // 2,359,296 B
    _Float16* vA   = (_Float16*)(ws + 4718592);         // 2,359,296 B (tile-blocked)
    short* attnbuf = (short*)(ws + 7077888);            // 2,359,296 B (bf16)
    short* Wt      = (short*)(ws + 9437184);            // 1,179,648 B
    short* Wot     = (short*)(ws + 10616832);           // 32,768 B
    short* Xt      = (short*)(ws + 10649600);           // 2,359,296 B

    transform_w<<<2944, 256, 0, stream>>>(wi, wq, wo, x, Wt, Wot, Xt);
    conv_main<<<dim3(48, 4, 4), 512, 0, stream>>>(Xt, Wt, dout, qT, kT, vA);
    attn_kernel<<<dim3(36, 32), 256, 0, stream>>>(qT, kT, vA, attnbuf);
    conv1x1<<<dim3(72, 4), 256, 0, stream>>>(attnbuf, Wot, dout);
}